// Round 7
// baseline (239.689 us; speedup 1.0000x reference)
//
#include <hip/hip_runtime.h>
#include <math.h>

#define S_LEN 2048
#define DM 1024

typedef __attribute__((ext_vector_type(8))) __bf16 bf16x8;
typedef __attribute__((ext_vector_type(4))) float floatx4;

typedef __attribute__((address_space(1))) const unsigned int g_u32;
typedef __attribute__((address_space(3))) unsigned int l_u32;

__device__ __forceinline__ unsigned short f2bf(float f) {
  union { float f; unsigned int u; } v; v.f = f;
  return (unsigned short)((v.u + 0x7fffu + ((v.u >> 16) & 1u)) >> 16);
}
__device__ __forceinline__ float bf2f(unsigned short u) {
  union { unsigned int u; float f; } v; v.u = ((unsigned int)u) << 16;
  return v.f;
}
__device__ __forceinline__ bf16x8 ld_frag(const unsigned short* p) {
  union { uint4 u; bf16x8 v; } t;
  t.u = *(const uint4*)p;
  return t.v;
}

// ---------------- dtype probe: 1 = buffers are fp32, 0 = bf16 ----------------
__global__ void detect_k(const unsigned short* __restrict__ x, int* __restrict__ flag) {
  __shared__ int cnt;
  if (threadIdx.x == 0) cnt = 0;
  __syncthreads();
  int local = 0;
  for (int i = threadIdx.x; i < 4096; i += 256) {
    unsigned short u = x[i];
    int e = (u >> 7) & 0xFF;
    if (e > 140) local++;
  }
  atomicAdd(&cnt, local);
  __syncthreads();
  if (threadIdx.x == 0) *flag = (cnt > 64) ? 1 : 0;
}

// ---------------- hidden-states conversion + windowed pre-scaled bias table ----------------
// blocks [0,2048): convert X to bf16 (8 elems/thread)
// blocks [2048,2072): bias window [16][384]: out[h][j] = bias(delta=j-192)*log2e - 24.
// Mixed attn tiles only touch deltas in [-173,173]; saturated tiles use endpoints.
__global__ void conv_bias(const void* __restrict__ src, unsigned short* __restrict__ dst,
                          const void* __restrict__ table, float* __restrict__ outb,
                          const int* __restrict__ flag) {
  const int bid = blockIdx.x, tid = threadIdx.x;
  if (bid < 2048) {
    int i = bid * 256 + tid;
    if (*flag) {
      const float4* s = (const float4*)src;
      float4 a = s[2 * i], b = s[2 * i + 1];
      union { uint4 u4; unsigned short s[8]; } o;
      o.s[0] = f2bf(a.x); o.s[1] = f2bf(a.y); o.s[2] = f2bf(a.z); o.s[3] = f2bf(a.w);
      o.s[4] = f2bf(b.x); o.s[5] = f2bf(b.y); o.s[6] = f2bf(b.z); o.s[7] = f2bf(b.w);
      ((uint4*)dst)[i] = o.u4;
    } else {
      ((uint4*)dst)[i] = ((const uint4*)src)[i];
    }
  } else {
    int idx = (bid - 2048) * 256 + tid;
    if (idx >= 16 * 384) return;
    int h = idx / 384;
    int j = idx - h * 384;
    int delta = j - 192;
    int bucket = (delta > 0) ? 16 : 0;
    int ad = (delta < 0) ? -delta : delta;
    int smallv;
    if (ad < 8) smallv = ad;
    else {
      int l = (int)(log((double)ad * 0.125) * (8.0 / log(16.0)));
      smallv = 8 + l;
      if (smallv > 15) smallv = 15;
    }
    bucket += smallv;
    float v;
    if (*flag) v = ((const float*)table)[bucket * 16 + h];
    else       v = bf2f(((const unsigned short*)table)[bucket * 16 + h]);
    outb[idx] = v * 1.44269504f - 24.f;
  }
}

// ---------------- transpose 1024x1024 weights -> bf16 W^T (4 mats, one launch) ----------------
__global__ void transpose_w(const void* __restrict__ s0, const void* __restrict__ s1,
                            const void* __restrict__ s2, const void* __restrict__ s3,
                            unsigned short* __restrict__ Wcat, unsigned short* __restrict__ Wto,
                            const int* __restrict__ flag) {
  __shared__ float tile[32][33];
  const int z = blockIdx.z;
  const void* src = (z == 0) ? s0 : (z == 1) ? s1 : (z == 2) ? s2 : s3;
  unsigned short* dst = (z < 3) ? (Wcat + (size_t)z * 1048576) : Wto;
  const int isf = *flag;
  int x = blockIdx.x * 32 + threadIdx.x;
  int y0 = blockIdx.y * 32;
  for (int i = threadIdx.y; i < 32; i += 8) {
    float v;
    if (isf) v = ((const float*)src)[(size_t)(y0 + i) * DM + x];
    else     v = bf2f(((const unsigned short*)src)[(size_t)(y0 + i) * DM + x]);
    tile[i][threadIdx.x] = v;
  }
  __syncthreads();
  int xo = y0 + threadIdx.x;
  for (int i = threadIdx.y; i < 32; i += 8)
    dst[(size_t)(blockIdx.x * 32 + i) * DM + xo] = f2bf(tile[threadIdx.x][i]);
}

// ---------------- fused QKV GEMM, m97-style; V^T epilogue via LDS transpose ----------------
__global__ __launch_bounds__(256) void gemm_bt(
    const unsigned short* __restrict__ A, const unsigned short* __restrict__ Bt,
    void* __restrict__ C)
{
  __shared__ __align__(16) unsigned short smem[128 * 136];  // As|Bs alias + transpose buf
  unsigned short* As = smem;          // 128*64
  unsigned short* Bs = smem + 8192;   // 128*64
  const int tid = threadIdx.x;
  const int lane = tid & 63, wave = tid >> 6;
  const int l16 = lane & 15, quad = lane >> 4;
  const int wm = (wave >> 1) << 6, wn = (wave & 1) << 6;
  const int m0 = blockIdx.y << 7, n0 = blockIdx.x << 7;
  const int lrow = lane >> 3, lcol = (lane & 7) << 3;

  floatx4 acc[4][4] = {};

  for (int k0 = 0; k0 < 1024; k0 += 64) {
    __syncthreads();
#pragma unroll
    for (int i = 0; i < 4; ++i) {
      int r0 = wave * 32 + i * 8;
      __builtin_amdgcn_global_load_lds(
          (g_u32*)(const void*)(A + (size_t)(m0 + r0 + lrow) * 1024 + k0 + lcol),
          (l_u32*)(void*)&As[r0 * 64], 16, 0, 0);
      __builtin_amdgcn_global_load_lds(
          (g_u32*)(const void*)(Bt + (size_t)(n0 + r0 + lrow) * 1024 + k0 + lcol),
          (l_u32*)(void*)&Bs[r0 * 64], 16, 0, 0);
    }
    __syncthreads();
#pragma unroll
    for (int ks = 0; ks < 2; ++ks) {
      bf16x8 a[4], b[4];
#pragma unroll
      for (int mi = 0; mi < 4; ++mi)
        a[mi] = *(const bf16x8*)&As[(wm + mi * 16 + l16) * 64 + ks * 32 + quad * 8];
#pragma unroll
      for (int ni = 0; ni < 4; ++ni)
        b[ni] = *(const bf16x8*)&Bs[(wn + ni * 16 + l16) * 64 + ks * 32 + quad * 8];
#pragma unroll
      for (int mi = 0; mi < 4; ++mi)
#pragma unroll
        for (int ni = 0; ni < 4; ++ni)
          acc[mi][ni] = __builtin_amdgcn_mfma_f32_16x16x32_bf16(a[mi], b[ni], acc[mi][ni], 0, 0, 0);
    }
  }

  unsigned short* Cs = (unsigned short*)C;
  const int mat = n0 >> 10;           // uniform per block
  if (mat < 2) {
#pragma unroll
    for (int mi = 0; mi < 4; ++mi)
#pragma unroll
      for (int ni = 0; ni < 4; ++ni)
#pragma unroll
        for (int i = 0; i < 4; ++i) {
          int m = m0 + wm + mi * 16 + quad * 4 + i;
          int n = (n0 & 1023) + wn + ni * 16 + l16;
          int b = m >> 11, s = m & 2047, h = n >> 6, d = n & 63;
          Cs[(size_t)mat * 4194304 + (((size_t)(b * 16 + h)) * 2048 + s) * 64 + d] =
              f2bf(acc[mi][ni][i]);
        }
  } else {
    // V^T via LDS transpose: T[n][m] then coalesced rows of V^T
    __syncthreads();  // all waves done with As/Bs
#pragma unroll
    for (int mi = 0; mi < 4; ++mi)
#pragma unroll
      for (int ni = 0; ni < 4; ++ni) {
        union { unsigned short s[4]; uint2 u; } w;
#pragma unroll
        for (int i = 0; i < 4; ++i) w.s[i] = f2bf(acc[mi][ni][i]);
        *(uint2*)&smem[(wn + ni * 16 + l16) * 136 + wm + mi * 16 + quad * 4] = w.u;
      }
    __syncthreads();
    const int bb = m0 >> 11, s0 = m0 & 2047, nb = n0 & 1023;
#pragma unroll
    for (int it = 0; it < 8; ++it) {
      int r = it * 16 + (tid >> 4);
      int c = (tid & 15) * 8;
      uint4 rv = *(const uint4*)&smem[r * 136 + c];
      *(uint4*)&Cs[(size_t)2 * 4194304 + (size_t)(bb * 1024 + nb + r) * 2048 + s0 + c] = rv;
    }
  }
}

// ---------------- out GEMM, 128x64 tiles (512 blocks = 2/CU) ----------------
__global__ __launch_bounds__(256) void gemm_out(
    const unsigned short* __restrict__ A, const unsigned short* __restrict__ Bt,
    void* __restrict__ C, const int* __restrict__ flag)
{
  __shared__ __align__(16) unsigned short As[128 * 64];
  __shared__ __align__(16) unsigned short Bs[64 * 64];
  const int tid = threadIdx.x;
  const int lane = tid & 63, wave = tid >> 6;
  const int l16 = lane & 15, quad = lane >> 4;
  const int wm = (wave >> 1) << 6, wn = (wave & 1) << 5;
  const int m0 = blockIdx.y << 7, n0 = blockIdx.x << 6;
  const int lrow = lane >> 3, lcol = (lane & 7) << 3;

  floatx4 acc[4][2] = {};

  for (int k0 = 0; k0 < 1024; k0 += 64) {
    __syncthreads();
#pragma unroll
    for (int i = 0; i < 4; ++i) {
      int r0 = wave * 32 + i * 8;
      __builtin_amdgcn_global_load_lds(
          (g_u32*)(const void*)(A + (size_t)(m0 + r0 + lrow) * 1024 + k0 + lcol),
          (l_u32*)(void*)&As[r0 * 64], 16, 0, 0);
    }
#pragma unroll
    for (int i = 0; i < 2; ++i) {
      int r0 = wave * 16 + i * 8;
      __builtin_amdgcn_global_load_lds(
          (g_u32*)(const void*)(Bt + (size_t)(n0 + r0 + lrow) * 1024 + k0 + lcol),
          (l_u32*)(void*)&Bs[r0 * 64], 16, 0, 0);
    }
    __syncthreads();
#pragma unroll
    for (int ks = 0; ks < 2; ++ks) {
      bf16x8 a[4], b[2];
#pragma unroll
      for (int mi = 0; mi < 4; ++mi)
        a[mi] = *(const bf16x8*)&As[(wm + mi * 16 + l16) * 64 + ks * 32 + quad * 8];
#pragma unroll
      for (int ni = 0; ni < 2; ++ni)
        b[ni] = *(const bf16x8*)&Bs[(wn + ni * 16 + l16) * 64 + ks * 32 + quad * 8];
#pragma unroll
      for (int mi = 0; mi < 4; ++mi)
#pragma unroll
        for (int ni = 0; ni < 2; ++ni)
          acc[mi][ni] = __builtin_amdgcn_mfma_f32_16x16x32_bf16(a[mi], b[ni], acc[mi][ni], 0, 0, 0);
    }
  }

  const int isf = *flag;
#pragma unroll
  for (int mi = 0; mi < 4; ++mi)
#pragma unroll
    for (int ni = 0; ni < 2; ++ni)
#pragma unroll
      for (int i = 0; i < 4; ++i) {
        int m = m0 + wm + mi * 16 + quad * 4 + i;
        int n = n0 + wn + ni * 16 + l16;
        size_t idx = (size_t)m * 1024 + n;
        float v = acc[mi][ni][i];
        if (isf) ((float*)C)[idx] = v;
        else     ((unsigned short*)C)[idx] = f2bf(v);
      }
}

// ---------------- flash attention: QBLK=64, 4 waves x 16 rows, 3 blocks/CU ----------------
// R6 (QBLK=128) = 74us at 2 blocks/CU (grid-limited): MFMA 18 + VALU 41 = 60%
// pipe use, ~40% latency stall that 2 waves/SIMD can't hide. Now grid (32,32)
// = 1024 blocks; LDS cut to 42.5 KB (bias windowed to 384 pre-scaled entries,
// saturated tiles use window endpoints) -> 3 blocks/CU = 3 waves/SIMD. Thin
// 16-row waves are safe here (unlike R1/R2) because K/V come from LDS, not
// global. Double-buffered staging (R6) unchanged.
#define STAGE_KV(kv0, buf)                                                    \
  _Pragma("unroll")                                                           \
  for (int i = 0; i < 2; ++i) {                                               \
    int rr = i * 32 + wave * 8 + (lane >> 3);                                 \
    int sw = ((lane & 7) ^ (lane >> 3)) << 3;                                 \
    __builtin_amdgcn_global_load_lds(                                         \
        (g_u32*)(const void*)(Kp + (size_t)((kv0) + rr) * 64 + sw),           \
        (l_u32*)(void*)&Ks[buf][i * 2048 + wave * 512], 16, 0, 0);            \
    __builtin_amdgcn_global_load_lds(                                         \
        (g_u32*)(const void*)(Vp + (size_t)rr * S_LEN + (kv0) + sw),          \
        (l_u32*)(void*)&Vs[buf][i * 2048 + wave * 512], 16, 0, 0);            \
  }

__global__ __launch_bounds__(256, 2) void attn_k(
    const unsigned short* __restrict__ Q, const unsigned short* __restrict__ K,
    const unsigned short* __restrict__ Vt, const float* __restrict__ bias,
    unsigned short* __restrict__ ctx)
{
  __shared__ __align__(16) unsigned short Ks[2][4096];     // K [64][64] x2, swizzled
  __shared__ __align__(16) unsigned short Vs[2][4096];     // V^T [64d][64kv] x2, swizzled
  __shared__ __align__(16) unsigned short Ps[4][16][72];   // wave-private, padded
  __shared__ float Bls[384];    // pre-scaled window: Bls[j] = b(delta=j-192)*log2e-24
  const int tid = threadIdx.x;
  const int lane = tid & 63, wave = tid >> 6;
  const int l16 = lane & 15, quad = lane >> 4;
  const int bh = blockIdx.y;
  const int b = bh >> 4, h = bh & 15;
  const int q0 = blockIdx.x << 6;
  const int wq = wave << 4;

  const unsigned short* Qp = Q + (size_t)bh * S_LEN * 64;
  const unsigned short* Kp = K + (size_t)bh * S_LEN * 64;
  const unsigned short* Vp = Vt + (size_t)bh * 64 * S_LEN;
  const float* biasg = bias + h * 384;

  // stage tile 0 + bias window + Q fragments before the first barrier
  STAGE_KV(0, 0);
  for (int i = tid; i < 384; i += 256) Bls[i] = biasg[i];

  bf16x8 qf[2];
#pragma unroll
  for (int ks = 0; ks < 2; ++ks)
    qf[ks] = ld_frag(Qp + (size_t)(q0 + wq + l16) * 64 + ks * 32 + quad * 8);

  float l_run[4] = {};
  floatx4 oacc[4] = {};

  const int qwb = q0 + wq;                          // wave's first q row
  const int rbase = 192 + l16 - (quad << 2) - qwb;  // window idx base minus kv0, i

  __syncthreads();  // tile 0 staged + bias visible
  const float Bneg = Bls[0], Bpos = Bls[383];       // saturated-bucket constants

  for (int kv0 = 0; kv0 < S_LEN; kv0 += 64) {
    const int cur = (kv0 >> 6) & 1;
    if (kv0 + 64 < S_LEN) STAGE_KV(kv0 + 64, cur ^ 1);  // hides under this tile

    // ---- QK^T from swizzled LDS K ----
    floatx4 sac[4] = {};
#pragma unroll
    for (int ks = 0; ks < 2; ++ks) {
      bf16x8 kf[4];
#pragma unroll
      for (int ni = 0; ni < 4; ++ni)
        kf[ni] = *(const bf16x8*)&Ks[cur][(ni * 16 + l16) * 64 +
                                          ((((ks << 2) + quad) ^ (l16 & 7)) << 3)];
#pragma unroll
      for (int ni = 0; ni < 4; ++ni)
        sac[ni] = __builtin_amdgcn_mfma_f32_16x16x32_bf16(qf[ks], kf[ni], sac[ni], 0, 0, 0);
    }

    // ---- fixed-max softmax (saturated-bucket fast path) ----
    {
      const int dmin = kv0 - (qwb + 15);
      const int dmax = kv0 + 63 - qwb;
      if (dmin >= 96 || dmax <= -96) {
        const float bc = (dmin >= 96) ? Bpos : Bneg;
#pragma unroll
        for (int i = 0; i < 4; ++i) {
          float sum = 0.f;
#pragma unroll
          for (int ni = 0; ni < 4; ++ni) {
            float e = __builtin_amdgcn_exp2f(fmaf(sac[ni][i], 1.44269504f, bc));
            sac[ni][i] = e; sum += e;
          }
          l_run[i] += sum;
        }
      } else {
#pragma unroll
        for (int i = 0; i < 4; ++i) {
          const int bbase = kv0 + rbase - i;
          float sum = 0.f;
#pragma unroll
          for (int ni = 0; ni < 4; ++ni) {
            float e = __builtin_amdgcn_exp2f(
                fmaf(sac[ni][i], 1.44269504f, Bls[bbase + ni * 16]));
            sac[ni][i] = e; sum += e;
          }
          l_run[i] += sum;
        }
      }
    }

    // ---- P -> LDS (wave-private, no barrier) ----
#pragma unroll
    for (int ni = 0; ni < 4; ++ni)
#pragma unroll
      for (int i = 0; i < 4; ++i)
        Ps[wave][quad * 4 + i][ni * 16 + l16] = f2bf(sac[ni][i]);

    // ---- PV from swizzled LDS V ----
#pragma unroll
    for (int ks2 = 0; ks2 < 2; ++ks2) {
      bf16x8 af, vf[4];
      af = *(const bf16x8*)&Ps[wave][l16][ks2 * 32 + quad * 8];
#pragma unroll
      for (int ni = 0; ni < 4; ++ni)
        vf[ni] = *(const bf16x8*)&Vs[cur][(ni * 16 + l16) * 64 +
                                          ((((ks2 << 2) + quad) ^ (l16 & 7)) << 3)];
#pragma unroll
      for (int ni = 0; ni < 4; ++ni)
        oacc[ni] = __builtin_amdgcn_mfma_f32_16x16x32_bf16(af, vf[ni], oacc[ni], 0, 0, 0);
    }

    __syncthreads();  // next-tile staging drained; everyone done with buf[cur]
  }

  // one-time cross-lane l reduction (columns live on the 16 lanes of each quad)
  float linv[4];
#pragma unroll
  for (int i = 0; i < 4; ++i) {
    float ls = l_run[i];
    ls += __shfl_xor(ls, 1);
    ls += __shfl_xor(ls, 2);
    ls += __shfl_xor(ls, 4);
    ls += __shfl_xor(ls, 8);
    linv[i] = 1.f / ls;
  }

#pragma unroll
  for (int ni = 0; ni < 4; ++ni)
#pragma unroll
    for (int i = 0; i < 4; ++i) {
      float v = oacc[ni][i] * linv[i];
      int srow = q0 + wq + quad * 4 + i;
      ctx[((size_t)(b * 2048 + srow)) * 1024 + h * 64 + ni * 16 + l16] = f2bf(v);
    }
}

extern "C" void kernel_launch(void* const* d_in, const int* in_sizes, int n_in,
                              void* d_out, int out_size, void* d_ws, size_t ws_size,
                              hipStream_t stream) {
  char* ws = (char*)d_ws;
  unsigned short* Xbf  = (unsigned short*)(ws);                    // 8 MB
  unsigned short* Wcat = (unsigned short*)(ws + 8388608);          // 6 MB (Wq^T|Wk^T|Wv^T)
  unsigned short* Wto  = (unsigned short*)(ws + 14680064);         // 2 MB
  unsigned short* Qb   = (unsigned short*)(ws + 16777216);         // 8 MB  (K at +8MB, Vt at +16MB)
  unsigned short* ctx  = (unsigned short*)(ws + 41943040);         // 8 MB
  float*          bias = (float*)(ws + 50331648);                  // 16*384*4 window
  int*            flag = (int*)(ws + 50593792);

  unsigned short* Kb  = Qb + 4194304;
  unsigned short* Vtb = Qb + 8388608;

  detect_k<<<1, 256, 0, stream>>>((const unsigned short*)d_in[0], flag);
  // conversion + windowed bias in one launch
  conv_bias<<<2072, 256, 0, stream>>>(d_in[0], Xbf, d_in[5], bias, flag);
  transpose_w<<<dim3(32, 32, 4), dim3(32, 8), 0, stream>>>(
      d_in[1], d_in[2], d_in[3], d_in[4], Wcat, Wto, flag);

  // fused QKV GEMM: [4096,1024] @ [3072,1024]^T -> Q|K|Vt (V^T via LDS transpose)
  gemm_bt<<<dim3(24, 32), 256, 0, stream>>>(Xbf, Wcat, Qb);

  // flash attention: QBLK=64, 1024 blocks, 3 blocks/CU
  attn_k<<<dim3(32, 32), 256, 0, stream>>>(Qb, Kb, Vtb, bias, ctx);

  // out GEMM: [4096,1024] @ [1024,1024]^T, 128x64 tiles
  gemm_out<<<dim3(16, 32), 256, 0, stream>>>(ctx, Wto, d_out, flag);
}

// Round 8
// 222.395 us; speedup vs baseline: 1.0778x; 1.0778x over previous
//
#include <hip/hip_runtime.h>
#include <math.h>

#define S_LEN 2048
#define DM 1024

typedef __attribute__((ext_vector_type(8))) __bf16 bf16x8;
typedef __attribute__((ext_vector_type(4))) float floatx4;

typedef __attribute__((address_space(1))) const unsigned int g_u32;
typedef __attribute__((address_space(3))) unsigned int l_u32;

__device__ __forceinline__ unsigned short f2bf(float f) {
  union { float f; unsigned int u; } v; v.f = f;
  return (unsigned short)((v.u + 0x7fffu + ((v.u >> 16) & 1u)) >> 16);
}
__device__ __forceinline__ float bf2f(unsigned short u) {
  union { unsigned int u; float f; } v; v.u = ((unsigned int)u) << 16;
  return v.f;
}
__device__ __forceinline__ bf16x8 ld_frag(const unsigned short* p) {
  union { uint4 u; bf16x8 v; } t;
  t.u = *(const uint4*)p;
  return t.v;
}

// ---------------- dtype probe: 1 = buffers are fp32, 0 = bf16 ----------------
__global__ void detect_k(const unsigned short* __restrict__ x, int* __restrict__ flag) {
  __shared__ int cnt;
  if (threadIdx.x == 0) cnt = 0;
  __syncthreads();
  int local = 0;
  for (int i = threadIdx.x; i < 4096; i += 256) {
    unsigned short u = x[i];
    int e = (u >> 7) & 0xFF;
    if (e > 140) local++;
  }
  atomicAdd(&cnt, local);
  __syncthreads();
  if (threadIdx.x == 0) *flag = (cnt > 64) ? 1 : 0;
}

// ---------------- hidden-states conversion + windowed pre-scaled bias table ----------------
// blocks [0,2048): convert X to bf16 (8 elems/thread)
// blocks [2048,2072): bias window [16][384]: out[h][j] = bias(delta=j-192)*log2e - 24.
// Mixed attn tiles only touch deltas in (-174,174); saturated tiles use endpoints.
__global__ void conv_bias(const void* __restrict__ src, unsigned short* __restrict__ dst,
                          const void* __restrict__ table, float* __restrict__ outb,
                          const int* __restrict__ flag) {
  const int bid = blockIdx.x, tid = threadIdx.x;
  if (bid < 2048) {
    int i = bid * 256 + tid;
    if (*flag) {
      const float4* s = (const float4*)src;
      float4 a = s[2 * i], b = s[2 * i + 1];
      union { uint4 u4; unsigned short s[8]; } o;
      o.s[0] = f2bf(a.x); o.s[1] = f2bf(a.y); o.s[2] = f2bf(a.z); o.s[3] = f2bf(a.w);
      o.s[4] = f2bf(b.x); o.s[5] = f2bf(b.y); o.s[6] = f2bf(b.z); o.s[7] = f2bf(b.w);
      ((uint4*)dst)[i] = o.u4;
    } else {
      ((uint4*)dst)[i] = ((const uint4*)src)[i];
    }
  } else {
    int idx = (bid - 2048) * 256 + tid;
    if (idx >= 16 * 384) return;
    int h = idx / 384;
    int j = idx - h * 384;
    int delta = j - 192;
    int bucket = (delta > 0) ? 16 : 0;
    int ad = (delta < 0) ? -delta : delta;
    int smallv;
    if (ad < 8) smallv = ad;
    else {
      int l = (int)(log((double)ad * 0.125) * (8.0 / log(16.0)));
      smallv = 8 + l;
      if (smallv > 15) smallv = 15;
    }
    bucket += smallv;
    float v;
    if (*flag) v = ((const float*)table)[bucket * 16 + h];
    else       v = bf2f(((const unsigned short*)table)[bucket * 16 + h]);
    outb[idx] = v * 1.44269504f - 24.f;
  }
}

// ---------------- transpose 1024x1024 weights -> bf16 W^T (4 mats, one launch) ----------------
__global__ void transpose_w(const void* __restrict__ s0, const void* __restrict__ s1,
                            const void* __restrict__ s2, const void* __restrict__ s3,
                            unsigned short* __restrict__ Wcat, unsigned short* __restrict__ Wto,
                            const int* __restrict__ flag) {
  __shared__ float tile[32][33];
  const int z = blockIdx.z;
  const void* src = (z == 0) ? s0 : (z == 1) ? s1 : (z == 2) ? s2 : s3;
  unsigned short* dst = (z < 3) ? (Wcat + (size_t)z * 1048576) : Wto;
  const int isf = *flag;
  int x = blockIdx.x * 32 + threadIdx.x;
  int y0 = blockIdx.y * 32;
  for (int i = threadIdx.y; i < 32; i += 8) {
    float v;
    if (isf) v = ((const float*)src)[(size_t)(y0 + i) * DM + x];
    else     v = bf2f(((const unsigned short*)src)[(size_t)(y0 + i) * DM + x]);
    tile[i][threadIdx.x] = v;
  }
  __syncthreads();
  int xo = y0 + threadIdx.x;
  for (int i = threadIdx.y; i < 32; i += 8)
    dst[(size_t)(blockIdx.x * 32 + i) * DM + xo] = f2bf(tile[threadIdx.x][i]);
}

// ---------------- fused QKV GEMM, m97-style; V^T epilogue via LDS transpose ----------------
__global__ __launch_bounds__(256) void gemm_bt(
    const unsigned short* __restrict__ A, const unsigned short* __restrict__ Bt,
    void* __restrict__ C)
{
  __shared__ __align__(16) unsigned short smem[128 * 136];  // As|Bs alias + transpose buf
  unsigned short* As = smem;          // 128*64
  unsigned short* Bs = smem + 8192;   // 128*64
  const int tid = threadIdx.x;
  const int lane = tid & 63, wave = tid >> 6;
  const int l16 = lane & 15, quad = lane >> 4;
  const int wm = (wave >> 1) << 6, wn = (wave & 1) << 6;
  const int m0 = blockIdx.y << 7, n0 = blockIdx.x << 7;
  const int lrow = lane >> 3, lcol = (lane & 7) << 3;

  floatx4 acc[4][4] = {};

  for (int k0 = 0; k0 < 1024; k0 += 64) {
    __syncthreads();
#pragma unroll
    for (int i = 0; i < 4; ++i) {
      int r0 = wave * 32 + i * 8;
      __builtin_amdgcn_global_load_lds(
          (g_u32*)(const void*)(A + (size_t)(m0 + r0 + lrow) * 1024 + k0 + lcol),
          (l_u32*)(void*)&As[r0 * 64], 16, 0, 0);
      __builtin_amdgcn_global_load_lds(
          (g_u32*)(const void*)(Bt + (size_t)(n0 + r0 + lrow) * 1024 + k0 + lcol),
          (l_u32*)(void*)&Bs[r0 * 64], 16, 0, 0);
    }
    __syncthreads();
#pragma unroll
    for (int ks = 0; ks < 2; ++ks) {
      bf16x8 a[4], b[4];
#pragma unroll
      for (int mi = 0; mi < 4; ++mi)
        a[mi] = *(const bf16x8*)&As[(wm + mi * 16 + l16) * 64 + ks * 32 + quad * 8];
#pragma unroll
      for (int ni = 0; ni < 4; ++ni)
        b[ni] = *(const bf16x8*)&Bs[(wn + ni * 16 + l16) * 64 + ks * 32 + quad * 8];
#pragma unroll
      for (int mi = 0; mi < 4; ++mi)
#pragma unroll
        for (int ni = 0; ni < 4; ++ni)
          acc[mi][ni] = __builtin_amdgcn_mfma_f32_16x16x32_bf16(a[mi], b[ni], acc[mi][ni], 0, 0, 0);
    }
  }

  unsigned short* Cs = (unsigned short*)C;
  const int mat = n0 >> 10;           // uniform per block
  if (mat < 2) {
#pragma unroll
    for (int mi = 0; mi < 4; ++mi)
#pragma unroll
      for (int ni = 0; ni < 4; ++ni)
#pragma unroll
        for (int i = 0; i < 4; ++i) {
          int m = m0 + wm + mi * 16 + quad * 4 + i;
          int n = (n0 & 1023) + wn + ni * 16 + l16;
          int b = m >> 11, s = m & 2047, h = n >> 6, d = n & 63;
          Cs[(size_t)mat * 4194304 + (((size_t)(b * 16 + h)) * 2048 + s) * 64 + d] =
              f2bf(acc[mi][ni][i]);
        }
  } else {
    // V^T via LDS transpose: T[n][m] then coalesced rows of V^T
    __syncthreads();  // all waves done with As/Bs
#pragma unroll
    for (int mi = 0; mi < 4; ++mi)
#pragma unroll
      for (int ni = 0; ni < 4; ++ni) {
        union { unsigned short s[4]; uint2 u; } w;
#pragma unroll
        for (int i = 0; i < 4; ++i) w.s[i] = f2bf(acc[mi][ni][i]);
        *(uint2*)&smem[(wn + ni * 16 + l16) * 136 + wm + mi * 16 + quad * 4] = w.u;
      }
    __syncthreads();
    const int bb = m0 >> 11, s0 = m0 & 2047, nb = n0 & 1023;
#pragma unroll
    for (int it = 0; it < 8; ++it) {
      int r = it * 16 + (tid >> 4);
      int c = (tid & 15) * 8;
      uint4 rv = *(const uint4*)&smem[r * 136 + c];
      *(uint4*)&Cs[(size_t)2 * 4194304 + (size_t)(bb * 1024 + nb + r) * 2048 + s0 + c] = rv;
    }
  }
}

// ---------------- out GEMM, 128x64 tiles (512 blocks = 2/CU) ----------------
__global__ __launch_bounds__(256) void gemm_out(
    const unsigned short* __restrict__ A, const unsigned short* __restrict__ Bt,
    void* __restrict__ C, const int* __restrict__ flag)
{
  __shared__ __align__(16) unsigned short As[128 * 64];
  __shared__ __align__(16) unsigned short Bs[64 * 64];
  const int tid = threadIdx.x;
  const int lane = tid & 63, wave = tid >> 6;
  const int l16 = lane & 15, quad = lane >> 4;
  const int wm = (wave >> 1) << 6, wn = (wave & 1) << 5;
  const int m0 = blockIdx.y << 7, n0 = blockIdx.x << 6;
  const int lrow = lane >> 3, lcol = (lane & 7) << 3;

  floatx4 acc[4][2] = {};

  for (int k0 = 0; k0 < 1024; k0 += 64) {
    __syncthreads();
#pragma unroll
    for (int i = 0; i < 4; ++i) {
      int r0 = wave * 32 + i * 8;
      __builtin_amdgcn_global_load_lds(
          (g_u32*)(const void*)(A + (size_t)(m0 + r0 + lrow) * 1024 + k0 + lcol),
          (l_u32*)(void*)&As[r0 * 64], 16, 0, 0);
    }
#pragma unroll
    for (int i = 0; i < 2; ++i) {
      int r0 = wave * 16 + i * 8;
      __builtin_amdgcn_global_load_lds(
          (g_u32*)(const void*)(Bt + (size_t)(n0 + r0 + lrow) * 1024 + k0 + lcol),
          (l_u32*)(void*)&Bs[r0 * 64], 16, 0, 0);
    }
    __syncthreads();
#pragma unroll
    for (int ks = 0; ks < 2; ++ks) {
      bf16x8 a[4], b[2];
#pragma unroll
      for (int mi = 0; mi < 4; ++mi)
        a[mi] = *(const bf16x8*)&As[(wm + mi * 16 + l16) * 64 + ks * 32 + quad * 8];
#pragma unroll
      for (int ni = 0; ni < 2; ++ni)
        b[ni] = *(const bf16x8*)&Bs[(wn + ni * 16 + l16) * 64 + ks * 32 + quad * 8];
#pragma unroll
      for (int mi = 0; mi < 4; ++mi)
#pragma unroll
        for (int ni = 0; ni < 2; ++ni)
          acc[mi][ni] = __builtin_amdgcn_mfma_f32_16x16x32_bf16(a[mi], b[ni], acc[mi][ni], 0, 0, 0);
    }
  }

  const int isf = *flag;
#pragma unroll
  for (int mi = 0; mi < 4; ++mi)
#pragma unroll
    for (int ni = 0; ni < 2; ++ni)
#pragma unroll
      for (int i = 0; i < 4; ++i) {
        int m = m0 + wm + mi * 16 + quad * 4 + i;
        int n = n0 + wn + ni * 16 + l16;
        size_t idx = (size_t)m * 1024 + n;
        float v = acc[mi][ni][i];
        if (isf) ((float*)C)[idx] = v;
        else     ((unsigned short*)C)[idx] = f2bf(v);
      }
}

// ---------------- flash attention: QBLK=128, 8 waves x 16 rows, 512 threads ----------------
// R6 (4wx32r, 2 blk/CU = 2 waves/SIMD) = 74us, ~40% latency stall. R7 (QBLK=64)
// regressed: halved per-block compute at same staging cost. This round keeps
// R6's block economics (128 q-rows, same staging per tile) but packs 8 thin
// waves -> 16 waves/CU = 4 waves/SIMD, deterministic (grid 512 = 2 blk/CU).
// Staging: 512 threads = exactly 1 global_load_lds per thread per tensor.
// launch_bounds(512,4) caps VGPR at 128 (R1/R2: never let allocator squeeze
// to 64; R3: never exceed 128).
#define STAGE_KV(kv0, buf)                                                    \
  {                                                                           \
    int rr = tid >> 3;                                                        \
    int sw = ((tid & 7) ^ (rr & 7)) << 3;                                     \
    __builtin_amdgcn_global_load_lds(                                         \
        (g_u32*)(const void*)(Kp + (size_t)((kv0) + rr) * 64 + sw),           \
        (l_u32*)(void*)&Ks[buf][wave * 512], 16, 0, 0);                       \
    __builtin_amdgcn_global_load_lds(                                         \
        (g_u32*)(const void*)(Vp + (size_t)rr * S_LEN + (kv0) + sw),          \
        (l_u32*)(void*)&Vs[buf][wave * 512], 16, 0, 0);                       \
  }

__global__ __launch_bounds__(512, 4) void attn_k(
    const unsigned short* __restrict__ Q, const unsigned short* __restrict__ K,
    const unsigned short* __restrict__ Vt, const float* __restrict__ bias,
    unsigned short* __restrict__ ctx)
{
  __shared__ __align__(16) unsigned short Ks[2][4096];     // K [64][64] x2, swizzled
  __shared__ __align__(16) unsigned short Vs[2][4096];     // V^T [64d][64kv] x2, swizzled
  __shared__ __align__(16) unsigned short Ps[8][16][72];   // wave-private, padded
  __shared__ float Bls[384];    // pre-scaled window: Bls[j] = b(delta=j-192)*log2e-24
  const int tid = threadIdx.x;
  const int lane = tid & 63, wave = tid >> 6;
  const int l16 = lane & 15, quad = lane >> 4;
  const int bh = blockIdx.y;
  const int b = bh >> 4, h = bh & 15;
  const int q0 = blockIdx.x << 7;
  const int wq = wave << 4;

  const unsigned short* Qp = Q + (size_t)bh * S_LEN * 64;
  const unsigned short* Kp = K + (size_t)bh * S_LEN * 64;
  const unsigned short* Vp = Vt + (size_t)bh * 64 * S_LEN;
  const float* biasg = bias + h * 384;

  // stage tile 0 + bias window + Q fragments before the first barrier
  STAGE_KV(0, 0);
  if (tid < 384) Bls[tid] = biasg[tid];

  bf16x8 qf[2];
#pragma unroll
  for (int ks = 0; ks < 2; ++ks)
    qf[ks] = ld_frag(Qp + (size_t)(q0 + wq + l16) * 64 + ks * 32 + quad * 8);

  float l_run[4] = {};
  floatx4 oacc[4] = {};

  const int qwb = q0 + wq;                          // wave's first q row
  const int rbase = 192 + l16 - (quad << 2) - qwb;  // window idx base minus kv0, i

  __syncthreads();  // tile 0 staged + bias visible
  const float Bneg = Bls[0], Bpos = Bls[383];       // saturated-bucket constants

  for (int kv0 = 0; kv0 < S_LEN; kv0 += 64) {
    const int cur = (kv0 >> 6) & 1;
    if (kv0 + 64 < S_LEN) STAGE_KV(kv0 + 64, cur ^ 1);  // hides under this tile

    // ---- QK^T from swizzled LDS K ----
    floatx4 sac[4] = {};
#pragma unroll
    for (int ks = 0; ks < 2; ++ks) {
      bf16x8 kf[4];
#pragma unroll
      for (int ni = 0; ni < 4; ++ni)
        kf[ni] = *(const bf16x8*)&Ks[cur][(ni * 16 + l16) * 64 +
                                          ((((ks << 2) + quad) ^ (l16 & 7)) << 3)];
#pragma unroll
      for (int ni = 0; ni < 4; ++ni)
        sac[ni] = __builtin_amdgcn_mfma_f32_16x16x32_bf16(qf[ks], kf[ni], sac[ni], 0, 0, 0);
    }

    // ---- fixed-max softmax (saturated-bucket fast path) ----
    {
      const int dmin = kv0 - (qwb + 15);
      const int dmax = kv0 + 63 - qwb;
      if (dmin >= 96 || dmax <= -96) {
        const float bc = (dmin >= 96) ? Bpos : Bneg;
#pragma unroll
        for (int i = 0; i < 4; ++i) {
          float sum = 0.f;
#pragma unroll
          for (int ni = 0; ni < 4; ++ni) {
            float e = __builtin_amdgcn_exp2f(fmaf(sac[ni][i], 1.44269504f, bc));
            sac[ni][i] = e; sum += e;
          }
          l_run[i] += sum;
        }
      } else {
#pragma unroll
        for (int i = 0; i < 4; ++i) {
          const int bbase = kv0 + rbase - i;
          float sum = 0.f;
#pragma unroll
          for (int ni = 0; ni < 4; ++ni) {
            float e = __builtin_amdgcn_exp2f(
                fmaf(sac[ni][i], 1.44269504f, Bls[bbase + ni * 16]));
            sac[ni][i] = e; sum += e;
          }
          l_run[i] += sum;
        }
      }
    }

    // ---- P -> LDS (wave-private, no barrier) ----
#pragma unroll
    for (int ni = 0; ni < 4; ++ni)
#pragma unroll
      for (int i = 0; i < 4; ++i)
        Ps[wave][quad * 4 + i][ni * 16 + l16] = f2bf(sac[ni][i]);

    // ---- PV from swizzled LDS V ----
#pragma unroll
    for (int ks2 = 0; ks2 < 2; ++ks2) {
      bf16x8 af, vf[4];
      af = *(const bf16x8*)&Ps[wave][l16][ks2 * 32 + quad * 8];
#pragma unroll
      for (int ni = 0; ni < 4; ++ni)
        vf[ni] = *(const bf16x8*)&Vs[cur][(ni * 16 + l16) * 64 +
                                          ((((ks2 << 2) + quad) ^ (l16 & 7)) << 3)];
#pragma unroll
      for (int ni = 0; ni < 4; ++ni)
        oacc[ni] = __builtin_amdgcn_mfma_f32_16x16x32_bf16(af, vf[ni], oacc[ni], 0, 0, 0);
    }

    __syncthreads();  // next-tile staging drained; everyone done with buf[cur]
  }

  // one-time cross-lane l reduction (columns live on the 16 lanes of each quad)
  float linv[4];
#pragma unroll
  for (int i = 0; i < 4; ++i) {
    float ls = l_run[i];
    ls += __shfl_xor(ls, 1);
    ls += __shfl_xor(ls, 2);
    ls += __shfl_xor(ls, 4);
    ls += __shfl_xor(ls, 8);
    linv[i] = 1.f / ls;
  }

#pragma unroll
  for (int ni = 0; ni < 4; ++ni)
#pragma unroll
    for (int i = 0; i < 4; ++i) {
      float v = oacc[ni][i] * linv[i];
      int srow = q0 + wq + quad * 4 + i;
      ctx[((size_t)(b * 2048 + srow)) * 1024 + h * 64 + ni * 16 + l16] = f2bf(v);
    }
}

extern "C" void kernel_launch(void* const* d_in, const int* in_sizes, int n_in,
                              void* d_out, int out_size, void* d_ws, size_t ws_size,
                              hipStream_t stream) {
  char* ws = (char*)d_ws;
  unsigned short* Xbf  = (unsigned short*)(ws);                    // 8 MB
  unsigned short* Wcat = (unsigned short*)(ws + 8388608);          // 6 MB (Wq^T|Wk^T|Wv^T)
  unsigned short* Wto  = (unsigned short*)(ws + 14680064);         // 2 MB
  unsigned short* Qb   = (unsigned short*)(ws + 16777216);         // 8 MB  (K at +8MB, Vt at +16MB)
  unsigned short* ctx  = (unsigned short*)(ws + 41943040);         // 8 MB
  float*          bias = (float*)(ws + 50331648);                  // 16*384*4 window
  int*            flag = (int*)(ws + 50593792);

  unsigned short* Kb  = Qb + 4194304;
  unsigned short* Vtb = Qb + 8388608;

  detect_k<<<1, 256, 0, stream>>>((const unsigned short*)d_in[0], flag);
  // conversion + windowed bias in one launch
  conv_bias<<<2072, 256, 0, stream>>>(d_in[0], Xbf, d_in[5], bias, flag);
  transpose_w<<<dim3(32, 32, 4), dim3(32, 8), 0, stream>>>(
      d_in[1], d_in[2], d_in[3], d_in[4], Wcat, Wto, flag);

  // fused QKV GEMM: [4096,1024] @ [3072,1024]^T -> Q|K|Vt (V^T via LDS transpose)
  gemm_bt<<<dim3(24, 32), 256, 0, stream>>>(Xbf, Wcat, Qb);

  // flash attention: QBLK=128, 8 waves x 16 rows, 512 threads, 4 waves/SIMD
  attn_k<<<dim3(16, 32), 512, 0, stream>>>(Qb, Kb, Vtb, bias, ctx);

  // out GEMM: [4096,1024] @ [1024,1024]^T, 128x64 tiles
  gemm_out<<<dim3(16, 32), 256, 0, stream>>>(ctx, Wto, d_out, flag);
}

// Round 9
// 217.310 us; speedup vs baseline: 1.1030x; 1.0234x over previous
//
#include <hip/hip_runtime.h>
#include <math.h>

#define S_LEN 2048
#define DM 1024

typedef __attribute__((ext_vector_type(8))) __bf16 bf16x8;
typedef __attribute__((ext_vector_type(4))) float floatx4;

typedef __attribute__((address_space(1))) const unsigned int g_u32;
typedef __attribute__((address_space(3))) unsigned int l_u32;

// native RNE f32->bf16 (compiler emits v_cvt_pk_bf16_f32; 1 op vs 3-op manual)
__device__ __forceinline__ unsigned short f2bf(float f) {
  union { __bf16 h; unsigned short u; } v;
  v.h = (__bf16)f;
  return v.u;
}
__device__ __forceinline__ float bf2f(unsigned short u) {
  union { unsigned int u; float f; } v; v.u = ((unsigned int)u) << 16;
  return v.f;
}
__device__ __forceinline__ bf16x8 ld_frag(const unsigned short* p) {
  union { uint4 u; bf16x8 v; } t;
  t.u = *(const uint4*)p;
  return t.v;
}

// ---------------- dtype probe (fallback only): 1 = fp32, 0 = bf16 ----------------
__global__ void detect_k(const unsigned short* __restrict__ x, int* __restrict__ flag) {
  __shared__ int cnt;
  if (threadIdx.x == 0) cnt = 0;
  __syncthreads();
  int local = 0;
  for (int i = threadIdx.x; i < 4096; i += 256) {
    unsigned short u = x[i];
    int e = (u >> 7) & 0xFF;
    if (e > 140) local++;
  }
  atomicAdd(&cnt, local);
  __syncthreads();
  if (threadIdx.x == 0) *flag = (cnt > 64) ? 1 : 0;
}

// ---------------- fused prep: X conversion + bias window + 4 weight transposes ----------------
// blocks [0,2048): convert X to bf16 (8 elems/thread)
// blocks [2048,2072): bias window [16][384]: out[h][j] = bias(delta=j-192)*log2e - 24
// blocks [2072,6168): transpose 4x 1024x1024 W -> bf16 W^T (32x32 tiles)
__global__ void prep_k(const void* __restrict__ x, unsigned short* __restrict__ dst,
                       const void* __restrict__ tbl, float* __restrict__ outb,
                       const void* __restrict__ w0, const void* __restrict__ w1,
                       const void* __restrict__ w2, const void* __restrict__ w3,
                       unsigned short* __restrict__ Wcat, unsigned short* __restrict__ Wto,
                       const int* __restrict__ flag) {
  __shared__ float tile[32][33];
  const int bid = blockIdx.x, tid = threadIdx.x;
  if (bid < 2048) {
    int i = bid * 256 + tid;
    if (*flag) {
      const float4* s = (const float4*)x;
      float4 a = s[2 * i], b = s[2 * i + 1];
      union { uint4 u4; unsigned short s[8]; } o;
      o.s[0] = f2bf(a.x); o.s[1] = f2bf(a.y); o.s[2] = f2bf(a.z); o.s[3] = f2bf(a.w);
      o.s[4] = f2bf(b.x); o.s[5] = f2bf(b.y); o.s[6] = f2bf(b.z); o.s[7] = f2bf(b.w);
      ((uint4*)dst)[i] = o.u4;
    } else {
      ((uint4*)dst)[i] = ((const uint4*)x)[i];
    }
  } else if (bid < 2072) {
    int idx = (bid - 2048) * 256 + tid;
    if (idx >= 16 * 384) return;
    int h = idx / 384;
    int j = idx - h * 384;
    int delta = j - 192;
    int bucket = (delta > 0) ? 16 : 0;
    int ad = (delta < 0) ? -delta : delta;
    int smallv;
    if (ad < 8) smallv = ad;
    else {
      int l = (int)(log((double)ad * 0.125) * (8.0 / log(16.0)));
      smallv = 8 + l;
      if (smallv > 15) smallv = 15;
    }
    bucket += smallv;
    float v;
    if (*flag) v = ((const float*)tbl)[bucket * 16 + h];
    else       v = bf2f(((const unsigned short*)tbl)[bucket * 16 + h]);
    outb[idx] = v * 1.44269504f - 24.f;
  } else {
    const int t = bid - 2072;
    const int z = t >> 10, rem = t & 1023;
    const int bx = rem & 31, by = rem >> 5;
    const int tx = tid & 31, ty = tid >> 5;
    const void* src = (z == 0) ? w0 : (z == 1) ? w1 : (z == 2) ? w2 : w3;
    unsigned short* dsty = (z < 3) ? (Wcat + (size_t)z * 1048576) : Wto;
    const int isf = *flag;
    int xc = bx * 32 + tx;
    int y0 = by * 32;
    for (int i = ty; i < 32; i += 8) {
      float v;
      if (isf) v = ((const float*)src)[(size_t)(y0 + i) * DM + xc];
      else     v = bf2f(((const unsigned short*)src)[(size_t)(y0 + i) * DM + xc]);
      tile[i][tx] = v;
    }
    __syncthreads();
    int xo = y0 + tx;
    for (int i = ty; i < 32; i += 8)
      dsty[(size_t)(bx * 32 + i) * DM + xo] = f2bf(tile[tx][i]);
  }
}

// ---------------- fused QKV GEMM, m97-style; V^T epilogue via LDS transpose ----------------
__global__ __launch_bounds__(256) void gemm_bt(
    const unsigned short* __restrict__ A, const unsigned short* __restrict__ Bt,
    void* __restrict__ C)
{
  __shared__ __align__(16) unsigned short smem[128 * 136];  // As|Bs alias + transpose buf
  unsigned short* As = smem;          // 128*64
  unsigned short* Bs = smem + 8192;   // 128*64
  const int tid = threadIdx.x;
  const int lane = tid & 63, wave = tid >> 6;
  const int l16 = lane & 15, quad = lane >> 4;
  const int wm = (wave >> 1) << 6, wn = (wave & 1) << 6;
  const int m0 = blockIdx.y << 7, n0 = blockIdx.x << 7;
  const int lrow = lane >> 3, lcol = (lane & 7) << 3;

  floatx4 acc[4][4] = {};

  for (int k0 = 0; k0 < 1024; k0 += 64) {
    __syncthreads();
#pragma unroll
    for (int i = 0; i < 4; ++i) {
      int r0 = wave * 32 + i * 8;
      __builtin_amdgcn_global_load_lds(
          (g_u32*)(const void*)(A + (size_t)(m0 + r0 + lrow) * 1024 + k0 + lcol),
          (l_u32*)(void*)&As[r0 * 64], 16, 0, 0);
      __builtin_amdgcn_global_load_lds(
          (g_u32*)(const void*)(Bt + (size_t)(n0 + r0 + lrow) * 1024 + k0 + lcol),
          (l_u32*)(void*)&Bs[r0 * 64], 16, 0, 0);
    }
    __syncthreads();
#pragma unroll
    for (int ks = 0; ks < 2; ++ks) {
      bf16x8 a[4], b[4];
#pragma unroll
      for (int mi = 0; mi < 4; ++mi)
        a[mi] = *(const bf16x8*)&As[(wm + mi * 16 + l16) * 64 + ks * 32 + quad * 8];
#pragma unroll
      for (int ni = 0; ni < 4; ++ni)
        b[ni] = *(const bf16x8*)&Bs[(wn + ni * 16 + l16) * 64 + ks * 32 + quad * 8];
#pragma unroll
      for (int mi = 0; mi < 4; ++mi)
#pragma unroll
        for (int ni = 0; ni < 4; ++ni)
          acc[mi][ni] = __builtin_amdgcn_mfma_f32_16x16x32_bf16(a[mi], b[ni], acc[mi][ni], 0, 0, 0);
    }
  }

  unsigned short* Cs = (unsigned short*)C;
  const int mat = n0 >> 10;           // uniform per block
  if (mat < 2) {
#pragma unroll
    for (int mi = 0; mi < 4; ++mi)
#pragma unroll
      for (int ni = 0; ni < 4; ++ni)
#pragma unroll
        for (int i = 0; i < 4; ++i) {
          int m = m0 + wm + mi * 16 + quad * 4 + i;
          int n = (n0 & 1023) + wn + ni * 16 + l16;
          int b = m >> 11, s = m & 2047, h = n >> 6, d = n & 63;
          Cs[(size_t)mat * 4194304 + (((size_t)(b * 16 + h)) * 2048 + s) * 64 + d] =
              f2bf(acc[mi][ni][i]);
        }
  } else {
    // V^T via LDS transpose: T[n][m] then coalesced rows of V^T
    __syncthreads();  // all waves done with As/Bs
#pragma unroll
    for (int mi = 0; mi < 4; ++mi)
#pragma unroll
      for (int ni = 0; ni < 4; ++ni) {
        union { unsigned short s[4]; uint2 u; } w;
#pragma unroll
        for (int i = 0; i < 4; ++i) w.s[i] = f2bf(acc[mi][ni][i]);
        *(uint2*)&smem[(wn + ni * 16 + l16) * 136 + wm + mi * 16 + quad * 4] = w.u;
      }
    __syncthreads();
    const int bb = m0 >> 11, s0 = m0 & 2047, nb = n0 & 1023;
#pragma unroll
    for (int it = 0; it < 8; ++it) {
      int r = it * 16 + (tid >> 4);
      int c = (tid & 15) * 8;
      uint4 rv = *(const uint4*)&smem[r * 136 + c];
      *(uint4*)&Cs[(size_t)2 * 4194304 + (size_t)(bb * 1024 + nb + r) * 2048 + s0 + c] = rv;
    }
  }
}

// ---------------- out GEMM, 128x64 tiles (512 blocks = 2/CU) ----------------
__global__ __launch_bounds__(256) void gemm_out(
    const unsigned short* __restrict__ A, const unsigned short* __restrict__ Bt,
    void* __restrict__ C, const int* __restrict__ flag)
{
  __shared__ __align__(16) unsigned short As[128 * 64];
  __shared__ __align__(16) unsigned short Bs[64 * 64];
  const int tid = threadIdx.x;
  const int lane = tid & 63, wave = tid >> 6;
  const int l16 = lane & 15, quad = lane >> 4;
  const int wm = (wave >> 1) << 6, wn = (wave & 1) << 5;
  const int m0 = blockIdx.y << 7, n0 = blockIdx.x << 6;
  const int lrow = lane >> 3, lcol = (lane & 7) << 3;

  floatx4 acc[4][2] = {};

  for (int k0 = 0; k0 < 1024; k0 += 64) {
    __syncthreads();
#pragma unroll
    for (int i = 0; i < 4; ++i) {
      int r0 = wave * 32 + i * 8;
      __builtin_amdgcn_global_load_lds(
          (g_u32*)(const void*)(A + (size_t)(m0 + r0 + lrow) * 1024 + k0 + lcol),
          (l_u32*)(void*)&As[r0 * 64], 16, 0, 0);
    }
#pragma unroll
    for (int i = 0; i < 2; ++i) {
      int r0 = wave * 16 + i * 8;
      __builtin_amdgcn_global_load_lds(
          (g_u32*)(const void*)(Bt + (size_t)(n0 + r0 + lrow) * 1024 + k0 + lcol),
          (l_u32*)(void*)&Bs[r0 * 64], 16, 0, 0);
    }
    __syncthreads();
#pragma unroll
    for (int ks = 0; ks < 2; ++ks) {
      bf16x8 a[4], b[2];
#pragma unroll
      for (int mi = 0; mi < 4; ++mi)
        a[mi] = *(const bf16x8*)&As[(wm + mi * 16 + l16) * 64 + ks * 32 + quad * 8];
#pragma unroll
      for (int ni = 0; ni < 2; ++ni)
        b[ni] = *(const bf16x8*)&Bs[(wn + ni * 16 + l16) * 64 + ks * 32 + quad * 8];
#pragma unroll
      for (int mi = 0; mi < 4; ++mi)
#pragma unroll
        for (int ni = 0; ni < 2; ++ni)
          acc[mi][ni] = __builtin_amdgcn_mfma_f32_16x16x32_bf16(a[mi], b[ni], acc[mi][ni], 0, 0, 0);
    }
  }

  const int isf = *flag;
#pragma unroll
  for (int mi = 0; mi < 4; ++mi)
#pragma unroll
    for (int ni = 0; ni < 2; ++ni)
#pragma unroll
      for (int i = 0; i < 4; ++i) {
        int m = m0 + wm + mi * 16 + quad * 4 + i;
        int n = n0 + wn + ni * 16 + l16;
        size_t idx = (size_t)m * 1024 + n;
        float v = acc[mi][ni][i];
        if (isf) ((float*)C)[idx] = v;
        else     ((unsigned short*)C)[idx] = f2bf(v);
      }
}

// ---------------- flash attention: QBLK=128, 8 waves x 16 rows; VALU-trimmed ----------------
// R8 analysis: kernel is VALU-issue-bound (VALUBusy 43 vs MfmaUtil 20; per-tile
// ~260 VALU-cy vs 80 MFMA-cy). This round deletes VALU:
//  - f2bf is now the native cast (v_cvt_pk_bf16_f32): P-store 48 -> ~16 ops/tile
//  - row sums l computed by a ones-column MFMA (lacc += P_frag x ones): removes
//    16 adds/tile AND the epilogue shuffle reduce; l sums the same bf16 P that
//    PV consumes (consistent numerator/denominator).
#define STAGE_KV(kv0, buf)                                                    \
  {                                                                           \
    int rr = tid >> 3;                                                        \
    int sw = ((tid & 7) ^ (rr & 7)) << 3;                                     \
    __builtin_amdgcn_global_load_lds(                                         \
        (g_u32*)(const void*)(Kp + (size_t)((kv0) + rr) * 64 + sw),           \
        (l_u32*)(void*)&Ks[buf][wave * 512], 16, 0, 0);                       \
    __builtin_amdgcn_global_load_lds(                                         \
        (g_u32*)(const void*)(Vp + (size_t)rr * S_LEN + (kv0) + sw),          \
        (l_u32*)(void*)&Vs[buf][wave * 512], 16, 0, 0);                       \
  }

__global__ __launch_bounds__(512, 4) void attn_k(
    const unsigned short* __restrict__ Q, const unsigned short* __restrict__ K,
    const unsigned short* __restrict__ Vt, const float* __restrict__ bias,
    unsigned short* __restrict__ ctx)
{
  __shared__ __align__(16) unsigned short Ks[2][4096];     // K [64][64] x2, swizzled
  __shared__ __align__(16) unsigned short Vs[2][4096];     // V^T [64d][64kv] x2, swizzled
  __shared__ __align__(16) unsigned short Ps[8][16][72];   // wave-private, padded
  __shared__ float Bls[384];    // pre-scaled window: Bls[j] = b(delta=j-192)*log2e-24
  const int tid = threadIdx.x;
  const int lane = tid & 63, wave = tid >> 6;
  const int l16 = lane & 15, quad = lane >> 4;
  const int bh = blockIdx.y;
  const int b = bh >> 4, h = bh & 15;
  const int q0 = blockIdx.x << 7;
  const int wq = wave << 4;

  const unsigned short* Qp = Q + (size_t)bh * S_LEN * 64;
  const unsigned short* Kp = K + (size_t)bh * S_LEN * 64;
  const unsigned short* Vp = Vt + (size_t)bh * 64 * S_LEN;
  const float* biasg = bias + h * 384;

  // stage tile 0 + bias window + Q fragments before the first barrier
  STAGE_KV(0, 0);
  if (tid < 384) Bls[tid] = biasg[tid];

  bf16x8 qf[2];
#pragma unroll
  for (int ks = 0; ks < 2; ++ks)
    qf[ks] = ld_frag(Qp + (size_t)(q0 + wq + l16) * 64 + ks * 32 + quad * 8);

  bf16x8 ones;
  {
    union { unsigned short s[8]; bf16x8 v; } o;
#pragma unroll
    for (int j = 0; j < 8; ++j) o.s[j] = 0x3F80;  // bf16 1.0
    ones = o.v;
  }

  floatx4 oacc[4] = {};
  floatx4 lacc = {};   // row sums of bf16 P via ones-MFMA

  const int qwb = q0 + wq;                          // wave's first q row
  const int rbase = 192 + l16 - (quad << 2) - qwb;  // window idx base minus kv0, i

  __syncthreads();  // tile 0 staged + bias visible
  const float Bneg = Bls[0], Bpos = Bls[383];       // saturated-bucket constants

  for (int kv0 = 0; kv0 < S_LEN; kv0 += 64) {
    const int cur = (kv0 >> 6) & 1;
    if (kv0 + 64 < S_LEN) STAGE_KV(kv0 + 64, cur ^ 1);  // hides under this tile

    // ---- QK^T from swizzled LDS K ----
    floatx4 sac[4] = {};
#pragma unroll
    for (int ks = 0; ks < 2; ++ks) {
      bf16x8 kf[4];
#pragma unroll
      for (int ni = 0; ni < 4; ++ni)
        kf[ni] = *(const bf16x8*)&Ks[cur][(ni * 16 + l16) * 64 +
                                          ((((ks << 2) + quad) ^ (l16 & 7)) << 3)];
#pragma unroll
      for (int ni = 0; ni < 4; ++ni)
        sac[ni] = __builtin_amdgcn_mfma_f32_16x16x32_bf16(qf[ks], kf[ni], sac[ni], 0, 0, 0);
    }

    // ---- fixed-max softmax (saturated-bucket fast path), no explicit row sums ----
    {
      const int dmin = kv0 - (qwb + 15);
      const int dmax = kv0 + 63 - qwb;
      if (dmin >= 96 || dmax <= -96) {
        const float bc = (dmin >= 96) ? Bpos : Bneg;
#pragma unroll
        for (int i = 0; i < 4; ++i)
#pragma unroll
          for (int ni = 0; ni < 4; ++ni)
            sac[ni][i] = __builtin_amdgcn_exp2f(fmaf(sac[ni][i], 1.44269504f, bc));
      } else {
#pragma unroll
        for (int i = 0; i < 4; ++i) {
          const int bbase = kv0 + rbase - i;
#pragma unroll
          for (int ni = 0; ni < 4; ++ni)
            sac[ni][i] = __builtin_amdgcn_exp2f(
                fmaf(sac[ni][i], 1.44269504f, Bls[bbase + ni * 16]));
        }
      }
    }

    // ---- P -> LDS (wave-private, no barrier) ----
#pragma unroll
    for (int ni = 0; ni < 4; ++ni)
#pragma unroll
      for (int i = 0; i < 4; ++i)
        Ps[wave][quad * 4 + i][ni * 16 + l16] = f2bf(sac[ni][i]);

    // ---- PV + row-sum MFMA from swizzled LDS V ----
#pragma unroll
    for (int ks2 = 0; ks2 < 2; ++ks2) {
      bf16x8 af, vf[4];
      af = *(const bf16x8*)&Ps[wave][l16][ks2 * 32 + quad * 8];
#pragma unroll
      for (int ni = 0; ni < 4; ++ni)
        vf[ni] = *(const bf16x8*)&Vs[cur][(ni * 16 + l16) * 64 +
                                          ((((ks2 << 2) + quad) ^ (l16 & 7)) << 3)];
#pragma unroll
      for (int ni = 0; ni < 4; ++ni)
        oacc[ni] = __builtin_amdgcn_mfma_f32_16x16x32_bf16(af, vf[ni], oacc[ni], 0, 0, 0);
      lacc = __builtin_amdgcn_mfma_f32_16x16x32_bf16(af, ones, lacc, 0, 0, 0);
    }

    __syncthreads();  // next-tile staging drained; everyone done with buf[cur]
  }

  // lacc[i] already holds the full row sum for q-row quad*4+i (all cols equal)
  float linv[4];
#pragma unroll
  for (int i = 0; i < 4; ++i) linv[i] = 1.f / lacc[i];

#pragma unroll
  for (int ni = 0; ni < 4; ++ni)
#pragma unroll
    for (int i = 0; i < 4; ++i) {
      float v = oacc[ni][i] * linv[i];
      int srow = q0 + wq + quad * 4 + i;
      ctx[((size_t)(b * 2048 + srow)) * 1024 + h * 64 + ni * 16 + l16] = f2bf(v);
    }
}

extern "C" void kernel_launch(void* const* d_in, const int* in_sizes, int n_in,
                              void* d_out, int out_size, void* d_ws, size_t ws_size,
                              hipStream_t stream) {
  char* ws = (char*)d_ws;
  unsigned short* Xbf  = (unsigned short*)(ws);                    // 8 MB
  unsigned short* Wcat = (unsigned short*)(ws + 8388608);          // 6 MB (Wq^T|Wk^T|Wv^T)
  unsigned short* Wto  = (unsigned short*)(ws + 14680064);         // 2 MB
  unsigned short* Qb   = (unsigned short*)(ws + 16777216);         // 8 MB  (K at +8MB, Vt at +16MB)
  unsigned short* ctx  = (unsigned short*)(ws + 41943040);         // 8 MB
  float*          bias = (float*)(ws + 50331648);                  // 16*384*4 window
  int*            flag = (int*)(ws + 50593792);

  unsigned short* Kb  = Qb + 4194304;
  unsigned short* Vtb = Qb + 8388608;

  // dtype from host-visible byte size when unambiguous (fp32 X = 16 MB, bf16 = 8 MB);
  // device probe only as fallback. memset 0x01010101 / 0x0 -- all readers test truthiness.
  int isf = -1;
  if (in_sizes && n_in > 0) {
    if (in_sizes[0] == 2 * 2048 * 1024 * 4) isf = 1;
    else if (in_sizes[0] == 2 * 2048 * 1024 * 2) isf = 0;
  }
  if (isf < 0)
    detect_k<<<1, 256, 0, stream>>>((const unsigned short*)d_in[0], flag);
  else
    hipMemsetAsync(flag, isf, sizeof(int), stream);

  // fused prep: X->bf16, bias window, 4 weight transposes (one launch)
  prep_k<<<6168, 256, 0, stream>>>(d_in[0], Xbf, d_in[5], bias,
                                   d_in[1], d_in[2], d_in[3], d_in[4],
                                   Wcat, Wto, flag);

  // fused QKV GEMM: [4096,1024] @ [3072,1024]^T -> Q|K|Vt (V^T via LDS transpose)
  gemm_bt<<<dim3(24, 32), 256, 0, stream>>>(Xbf, Wcat, Qb);

  // flash attention: QBLK=128, 8 waves x 16 rows, VALU-trimmed
  attn_k<<<dim3(16, 32), 512, 0, stream>>>(Qb, Kb, Vtb, bias, ctx);

  // out GEMM: [4096,1024] @ [1024,1024]^T, 128x64 tiles
  gemm_out<<<dim3(16, 32), 256, 0, stream>>>(ctx, Wto, d_out, flag);
}